// Round 5
// baseline (143.787 us; speedup 1.0000x reference)
//
#include <hip/hip_runtime.h>
#include <hip/hip_bf16.h>

#define B_ 2
#define H_ 16
#define HKV_ 4
#define S_ 4096
#define D_ 64
#define BN_ 64
#define NB_ 64
#define BPQ_ 6
#define QSCALE_LOG2 0.18033688f   // (1/sqrt(64)) * log2(e)
#define LOG2E 1.44269504f
#define LDK 72      // padded LDS row stride (bf16 elems), rows 16B-aligned
#define NSPLIT0 4   // qb==0 split factor
#define PART_ 4224  // per-(bh,split) ws floats: 4096 o + 64 m + 64 l

typedef short bf16x8 __attribute__((ext_vector_type(8)));
typedef short bf16x4v __attribute__((ext_vector_type(4)));
typedef float f32x4 __attribute__((ext_vector_type(4)));
typedef unsigned int u32x4 __attribute__((ext_vector_type(4)));

static __device__ __forceinline__ short f2bf(float f) {
    unsigned u = __builtin_bit_cast(unsigned, f);
    unsigned r = u + 0x7FFFu + ((u >> 16) & 1u);   // RNE (finite normals)
    return (short)(r >> 16);
}

static __device__ __forceinline__ unsigned cvt_pk_bf16(float lo, float hi) {
    unsigned r;
    asm("v_cvt_pk_bf16_f32 %0, %1, %2" : "=v"(r) : "v"(lo), "v"(hi));
    return r;   // low16 = bf16(lo), high16 = bf16(hi)
}

// LDS map (bytes):
//   [0,18432)      kc[2][64][LDK] shorts   (stream-indexed K tiles)
//   [18432,36864)  vt[2][64][LDK] shorts   (stream-indexed V^T tiles, col-swizzled)
// merge phase aliases:
//   [0,17408)      obuf[64][68] floats     (stream1 O^T dump)
//   [18432,18944)  ml[128] floats          (stream1 m,l)
__global__ __launch_bounds__(512) void sparse_attn_main(
    const float* __restrict__ q,
    const float* __restrict__ k,
    const float* __restrict__ v,
    const int* __restrict__ seg,
    const int* __restrict__ bidx,
    const float* __restrict__ slopes,
    float* __restrict__ out,
    float* __restrict__ ws)
{
    __shared__ __align__(16) char smem[36864];
    __shared__ int vlist[17];
    __shared__ int vcount;

    const int qbx  = blockIdx.x;        // 0..NB_+2
    int qb, split;
    if (qbx < NB_) { qb = qbx; split = 0; }
    else           { qb = 0;   split = qbx - (NB_ - 1); }   // 64,65,66 -> 1,2,3
    const bool split_path = (qb == 0);

    const int bh   = blockIdx.y;
    const int b    = bh / H_;
    const int h    = bh % H_;
    const int hkv  = h / (H_ / HKV_);
    const int tid  = threadIdx.x;
    const int wave = tid >> 6;
    const int strm = wave >> 2;         // 0,1: chunk stream
    const int w4   = wave & 3;          // q-row group within stream
    const int lane = tid & 63;
    const int l16  = lane & 15;
    const int lhi  = lane >> 4;         // 0..3
    const int tis  = tid & 255;         // within-stream thread id

    short* kcp = (short*)smem + strm * 4608;             // 64*LDK
    short* vtp = (short*)(smem + 18432) + strm * 4608;

    const float slope2 = slopes[h] * LOG2E;
    const int   qseg   = seg[b * S_ + qb * BN_];

    // ---- valid-chunk list (lane-parallel, wave 0) ----
    if (wave == 0) {
        const int n = split_path ? 16 : (1 + BPQ_);
        int cand = -1;
        if (lane < n) {
            if (split_path)       cand = split + 4 * lane;       // strided quarters
            else if (lane == 0)   cand = 0;                      // global block
            else                  cand = bidx[qb * BPQ_ + lane - 1];
        }
        bool ok = false;
        if (cand >= 0) {
            int ks_ = seg[b * S_ + cand * BN_];
            ok = (qseg >= 0) && (ks_ == qseg);
        }
        unsigned long long m = __ballot(ok);
        if (ok) {
            int rank = __popcll(m & ((1ull << lane) - 1ull));
            vlist[rank] = cand;
        }
        if (lane == 0) vcount = (int)__popcll(m);
    }

    // ---- Q fragment (MFMA B operand), SCALE*log2e folded in ----
    const int qrow = qb * BN_ + w4 * 16 + l16;
    const float qpos = (float)qrow;
    const float* qp = q + (((size_t)(b * H_ + h)) * S_ + qrow) * D_;
    bf16x8 qf[2];
#pragma unroll
    for (int kk = 0; kk < 2; ++kk)
#pragma unroll
        for (int i = 0; i < 8; ++i)
            qf[kk][i] = f2bf(qp[kk * 32 + lhi * 8 + i] * QSCALE_LOG2);

    // O^T accumulators: oacc[dt] reg r -> row d = 16dt+4lhi+r, col q = l16
    f32x4 oacc[4] = {};
    float mrun = -1e30f, lrun = 0.f;    // log2 domain

    const float* kb_ptr = k + ((size_t)(b * HKV_ + hkv)) * S_ * D_;
    const float* vb_ptr = v + ((size_t)(b * HKV_ + hkv)) * S_ * D_;

    __syncthreads();
    const int nval = vcount;
    const int nr   = (nval + 1) >> 1;   // rounds (both streams hit same barriers)

    float4 kr0, kr1, kr2, kr3, vr0, vr1, vr2, vr3;
#define ISSUE_LOADS(CBLK) do { \
        const float4* ks_ = (const float4*)(kb_ptr + (size_t)(CBLK) * (BN_ * D_)); \
        const float4* vs_ = (const float4*)(vb_ptr + (size_t)(CBLK) * (BN_ * D_)); \
        kr0 = ks_[tis];       kr1 = ks_[tis + 256]; \
        kr2 = ks_[tis + 512]; kr3 = ks_[tis + 768]; \
        vr0 = vs_[tis];       vr1 = vs_[tis + 256]; \
        vr2 = vs_[tis + 512]; vr3 = vs_[tis + 768]; \
    } while (0)

    // thread holds one key (4 d). kc: packed b64 write. vt: 4 scalar writes,
    // key col XOR-swizzled by 8*((d>>2)&7).
#define WRITE_STAGE(IT, KR, VR) do { \
        int idx_ = tis + (IT) * 256; \
        int key_ = idx_ >> 4; \
        int d0_  = (idx_ & 15) * 4; \
        unsigned p0_ = cvt_pk_bf16(KR.x, KR.y); \
        unsigned p1_ = cvt_pk_bf16(KR.z, KR.w); \
        uint2 kp_ = { p0_, p1_ }; \
        *(uint2*)&kcp[key_ * LDK + d0_] = kp_; \
        int sw_ = key_ ^ (((d0_ >> 2) & 7) << 3); \
        vtp[(d0_ + 0) * LDK + sw_] = f2bf(VR.x); \
        vtp[(d0_ + 1) * LDK + sw_] = f2bf(VR.y); \
        vtp[(d0_ + 2) * LDK + sw_] = f2bf(VR.z); \
        vtp[(d0_ + 3) * LDK + sw_] = f2bf(VR.w); \
    } while (0)

    if (strm < nval) ISSUE_LOADS(vlist[strm]);

    for (int r = 0; r < nr; ++r) {
        const int c = 2 * r + strm;
        const bool have = (c < nval);
        const int kbase = have ? vlist[c] * BN_ : 0;

        __syncthreads();                 // prior round's LDS readers done
        if (have) {
            WRITE_STAGE(0, kr0, vr0);
            WRITE_STAGE(1, kr1, vr1);
            WRITE_STAGE(2, kr2, vr2);
            WRITE_STAGE(3, kr3, vr3);
            if (c + 2 < nval) ISSUE_LOADS(vlist[c + 2]);   // prefetch own stream's next
        }
        __syncthreads();                 // staging visible
        if (!have) continue;

        // ---- swapped QK^T: S^T = K * Q^T ----
        f32x4 sacc[4];
#pragma unroll
        for (int nt = 0; nt < 4; ++nt) {
            f32x4 s = {};
#pragma unroll
            for (int kk = 0; kk < 2; ++kk) {
                bf16x8 kf_ = *(const bf16x8*)&kcp[(nt * 16 + l16) * LDK + kk * 32 + lhi * 8];
                s = __builtin_amdgcn_mfma_f32_16x16x32_bf16(kf_, qf[kk], s, 0, 0, 0);
            }
            sacc[nt] = s;
        }

        // ---- online softmax, log2 domain (q = l16 per lane) ----
        const float dbase = qpos - (float)(kbase + lhi * 4);
        float p_[4][4];
        float mx = -1e30f;
#pragma unroll
        for (int nt = 0; nt < 4; ++nt)
#pragma unroll
            for (int r2 = 0; r2 < 4; ++r2) {
                float sc = fmaf(-slope2, fabsf(dbase - (float)(nt * 16 + r2)), sacc[nt][r2]);
                p_[nt][r2] = sc;
                mx = fmaxf(mx, sc);
            }
        mx = fmaxf(mx, __shfl_xor(mx, 16));
        mx = fmaxf(mx, __shfl_xor(mx, 32));
        const float mn = fmaxf(mrun, mx);
        float sum = 0.f;
#pragma unroll
        for (int nt = 0; nt < 4; ++nt)
#pragma unroll
            for (int r2 = 0; r2 < 4; ++r2) {
                float p = exp2f(p_[nt][r2] - mn);
                p_[nt][r2] = p;
                sum += p;
            }
        sum += __shfl_xor(sum, 16);
        sum += __shfl_xor(sum, 32);
        const float corr = exp2f(mrun - mn);
        mrun = mn;
        lrun = lrun * corr + sum;
#pragma unroll
        for (int dt = 0; dt < 4; ++dt) oacc[dt] *= corr;

        // ---- P^T -> bf16 in-lane ----
        unsigned pk_[4][2];
#pragma unroll
        for (int nt = 0; nt < 4; ++nt) {
            pk_[nt][0] = cvt_pk_bf16(p_[nt][0], p_[nt][1]);
            pk_[nt][1] = cvt_pk_bf16(p_[nt][2], p_[nt][3]);
        }

        // ---- PV: O^T += V^T * P^T (k-slot perm: key = 32kk+16(i>>2)+4lhi+(i&3)) ----
#pragma unroll
        for (int kk = 0; kk < 2; ++kk) {
            u32x4 pw = { pk_[2 * kk][0], pk_[2 * kk][1],
                         pk_[2 * kk + 1][0], pk_[2 * kk + 1][1] };
            bf16x8 pf = __builtin_bit_cast(bf16x8, pw);
#pragma unroll
            for (int dt = 0; dt < 4; ++dt) {
                const short* vrow = &vtp[(dt * 16 + l16) * LDK];
                const int sv8 = ((4 * dt + (l16 >> 2)) & 7) << 3;
                bf16x4v lo = *(const bf16x4v*)&vrow[(kk * 32 + 4 * lhi) ^ sv8];
                bf16x4v hi = *(const bf16x4v*)&vrow[(kk * 32 + 16 + 4 * lhi) ^ sv8];
                bf16x8 vf = __builtin_shufflevector(lo, hi, 0, 1, 2, 3, 4, 5, 6, 7);
                oacc[dt] = __builtin_amdgcn_mfma_f32_16x16x32_bf16(vf, pf, oacc[dt], 0, 0, 0);
            }
        }
    }

    // ---- merge stream1 into stream0 via LDS ----
    float* obuf = (float*)smem;                 // [64][68]
    float* ml   = (float*)(smem + 18432);       // m:[0..63] l:[64..127]
    __syncthreads();                            // all compute done
    if (strm == 1) {
        float* orow = obuf + (w4 * 16 + l16) * 68;
#pragma unroll
        for (int dt = 0; dt < 4; ++dt) {
            float4 o4 = { oacc[dt][0], oacc[dt][1], oacc[dt][2], oacc[dt][3] };
            *(float4*)&orow[dt * 16 + 4 * lhi] = o4;
        }
        if (lhi == 0) {
            ml[w4 * 16 + l16]      = mrun;
            ml[64 + w4 * 16 + l16] = lrun;
        }
    }
    __syncthreads();
    if (strm != 0) return;

    const float m1 = ml[w4 * 16 + l16];
    const float l1 = ml[64 + w4 * 16 + l16];
    const float mM = fmaxf(mrun, m1);
    const float w0 = exp2f(mrun - mM);
    const float w1 = exp2f(m1 - mM);
    const float lM = w0 * lrun + w1 * l1;
    const float* orow = obuf + (w4 * 16 + l16) * 68;
#pragma unroll
    for (int dt = 0; dt < 4; ++dt) {
        float4 o4 = *(const float4*)&orow[dt * 16 + 4 * lhi];
        f32x4 o1 = { o4.x, o4.y, o4.z, o4.w };
        oacc[dt] = oacc[dt] * w0 + o1 * w1;
    }

    // ---- epilogue ----
    if (split_path) {
        float* wsp = ws + (size_t)(bh * NSPLIT0 + split) * PART_;
        const int m = w4 * 16 + l16;
#pragma unroll
        for (int dt = 0; dt < 4; ++dt) {
            float4 o4 = { oacc[dt][0], oacc[dt][1], oacc[dt][2], oacc[dt][3] };
            *(float4*)&wsp[m * D_ + dt * 16 + 4 * lhi] = o4;   // unnormalized
        }
        if (lhi == 0) {
            wsp[4096 + m] = mM;     // log2 domain
            wsp[4160 + m] = lM;
        }
    } else {
        const float inv = 1.0f / (lM == 0.f ? 1.f : lM);
        float* op = out + ((size_t)bh * S_ + qrow) * D_;
#pragma unroll
        for (int dt = 0; dt < 4; ++dt) {
            float4 o4 = { oacc[dt][0] * inv, oacc[dt][1] * inv,
                          oacc[dt][2] * inv, oacc[dt][3] * inv };
            *(float4*)&op[dt * 16 + 4 * lhi] = o4;
        }
    }
}

__global__ __launch_bounds__(256) void sparse_attn_combine(
    const float* __restrict__ ws,
    float* __restrict__ out)
{
    const int bh  = blockIdx.x;          // 0..31
    const int t   = threadIdx.x;
    const int row = t >> 2;              // 0..63
    const int d0  = (t & 3) * 16;

    const float* base = ws + (size_t)bh * NSPLIT0 * PART_;
    float ms[NSPLIT0], ls[NSPLIT0];
    float M = -1e30f;
#pragma unroll
    for (int s = 0; s < NSPLIT0; ++s) {
        ms[s] = base[s * PART_ + 4096 + row];
        ls[s] = base[s * PART_ + 4160 + row];
        M = fmaxf(M, ms[s]);
    }
    float w[NSPLIT0];
    float L = 0.f;
#pragma unroll
    for (int s = 0; s < NSPLIT0; ++s) {
        w[s] = exp2f(ms[s] - M);        // log2 domain
        L += w[s] * ls[s];
    }
    const float inv = 1.0f / (L == 0.f ? 1.f : L);

    float* op = out + ((size_t)bh * S_ + row) * D_ + d0;
#pragma unroll
    for (int j = 0; j < 16; ++j) {
        float acc = 0.f;
#pragma unroll
        for (int s = 0; s < NSPLIT0; ++s)
            acc += w[s] * base[s * PART_ + row * D_ + d0 + j];
        op[j] = acc * inv;
    }
}

extern "C" void kernel_launch(void* const* d_in, const int* in_sizes, int n_in,
                              void* d_out, int out_size, void* d_ws, size_t ws_size,
                              hipStream_t stream) {
    const float* q      = (const float*)d_in[0];
    const float* k      = (const float*)d_in[1];
    const float* v      = (const float*)d_in[2];
    const int*   seg    = (const int*)d_in[3];
    const int*   bidx   = (const int*)d_in[4];
    const float* slopes = (const float*)d_in[5];
    float*       out    = (float*)d_out;
    float*       ws     = (float*)d_ws;

    dim3 grid(NB_ + (NSPLIT0 - 1), B_ * H_);
    sparse_attn_main<<<grid, 512, 0, stream>>>(q, k, v, seg, bidx, slopes, out, ws);
    sparse_attn_combine<<<dim3(B_ * H_), 256, 0, stream>>>(ws, out);
}